// Round 1
// baseline (1674.460 us; speedup 1.0000x reference)
//
#include <hip/hip_runtime.h>

// AttentionPooling: s = tanh(x@W1+b1)@w2 (+b2, dropped: softmax-invariant);
// segment softmax over sorted batch; pooled = segsum(alpha*x); out = pooled@Wp+bp.
// N=1e6, D=256, B=4096. Strategy: bf16-MFMA fused score kernel (memory-bound on
// the 1 GB x stream), block-per-segment softmax+pooling (second 1 GB x stream),
// small fp32 GEMM epilogue. ~320 us HBM roofline for the two x passes.

typedef __bf16 bf16_t;
typedef __attribute__((ext_vector_type(8))) __bf16 bf16x8;
typedef __attribute__((ext_vector_type(4))) float f32x4;

constexpr int D = 256;

// ---------------------------------------------------------------------------
// Repack W1 (fp32 row-major KxN, K=input dim) into bf16 MFMA B-fragment order:
// for tile j (16 output cols), k-step kk (32 k), lane: 8 bf16 with
// k = kk*32 + (lane>>4)*8 + t, n = j*16 + (lane&15). One dwordx4 per lane later.
__global__ void prep_wfrag_kernel(const float* __restrict__ W1,
                                  bf16_t* __restrict__ wfrag) {
    int tid = blockIdx.x * blockDim.x + threadIdx.x;  // 16*8*64 = 8192 threads
    if (tid >= 16 * 8 * 64) return;
    int lane = tid & 63;
    int kk   = (tid >> 6) & 7;
    int j    = tid >> 9;
    int quad = lane >> 4, col = lane & 15;
    const float* src = W1 + (size_t)(kk * 32 + quad * 8) * D + j * 16 + col;
    bf16_t* dst = wfrag + (size_t)tid * 8;
#pragma unroll
    for (int t = 0; t < 8; ++t) dst[t] = (bf16_t)src[(size_t)t * D];
}

// ---------------------------------------------------------------------------
// Score kernel: 256 points/block, 4 waves, each wave 64 rows (4 strips of 16).
// A-fragments straight from global x (16 rows x 128B contiguous per wave-load).
// C/D layout (verified): col = lane&15, row = (lane>>4)*4 + reg.
__global__ __launch_bounds__(256, 2) void scores_kernel(
    const float* __restrict__ x, const bf16_t* __restrict__ wfrag,
    const float* __restrict__ b1, const float* __restrict__ w2,
    float* __restrict__ s, int N) {
    const int lane = threadIdx.x & 63;
    const int wave = threadIdx.x >> 6;
    const int quad = lane >> 4;
    const int col  = lane & 15;
    const long base = (long)blockIdx.x * 256 + wave * 64;

    // Load all A fragments: A[m = lane&15][k = quad*8 + t], k-block kk.
    bf16x8 A[4][8];
#pragma unroll
    for (int st = 0; st < 4; ++st) {
        long row = base + st * 16 + col;
        if (row >= N) row = N - 1;  // pad rows: harmless dup, output guarded
        const float* xp = x + row * (long)D + quad * 8;
#pragma unroll
        for (int kk = 0; kk < 8; ++kk) {
            float4 u0 = *(const float4*)(xp + kk * 32);
            float4 u1 = *(const float4*)(xp + kk * 32 + 4);
            bf16x8 a;
            a[0] = (bf16_t)u0.x; a[1] = (bf16_t)u0.y;
            a[2] = (bf16_t)u0.z; a[3] = (bf16_t)u0.w;
            a[4] = (bf16_t)u1.x; a[5] = (bf16_t)u1.y;
            a[6] = (bf16_t)u1.z; a[7] = (bf16_t)u1.w;
            A[st][kk] = a;
        }
    }

    float spart[4][4];
#pragma unroll
    for (int st = 0; st < 4; ++st)
#pragma unroll
        for (int r = 0; r < 4; ++r) spart[st][r] = 0.f;

    for (int j = 0; j < 16; ++j) {  // 16 col-tiles of h
        f32x4 C[4];
#pragma unroll
        for (int st = 0; st < 4; ++st)
#pragma unroll
            for (int r = 0; r < 4; ++r) C[st][r] = 0.f;
#pragma unroll
        for (int kk = 0; kk < 8; ++kk) {
            bf16x8 Bf = *(const bf16x8*)(wfrag +
                        (size_t)((j * 8 + kk) * 64 + lane) * 8);
#pragma unroll
            for (int st = 0; st < 4; ++st)
                C[st] = __builtin_amdgcn_mfma_f32_16x16x32_bf16(
                    A[st][kk], Bf, C[st], 0, 0, 0);
        }
        // epilogue: s += tanh(h + b1) * w2 for column n = j*16+col
        int n = j * 16 + col;
        float w2n = w2[n];
        float b1n = b1[n];
#pragma unroll
        for (int st = 0; st < 4; ++st)
#pragma unroll
            for (int r = 0; r < 4; ++r) {
                float h = C[st][r] + b1n;
                float e = __expf(2.f * h);          // tanh = 1 - 2/(e^{2h}+1)
                spart[st][r] += (1.f - 2.f / (e + 1.f)) * w2n;
            }
    }
    // reduce over the 16 column-lanes of each quad
#pragma unroll
    for (int o = 1; o < 16; o <<= 1)
#pragma unroll
        for (int st = 0; st < 4; ++st)
#pragma unroll
            for (int r = 0; r < 4; ++r)
                spart[st][r] += __shfl_xor(spart[st][r], o, 64);
    if (col == 0) {
#pragma unroll
        for (int st = 0; st < 4; ++st)
#pragma unroll
            for (int r = 0; r < 4; ++r) {
                long row = base + st * 16 + quad * 4 + r;
                if (row < N) s[row] = spart[st][r];
            }
    }
}

// ---------------------------------------------------------------------------
// off[b] = lower_bound(batch, b) for b in [0, B]; batch is sorted int32.
__global__ void seg_offsets_kernel(const int* __restrict__ batch,
                                   int* __restrict__ off, int N, int B) {
    int b = blockIdx.x * blockDim.x + threadIdx.x;
    if (b > B) return;
    int lo = 0, hi = N;
    while (lo < hi) {
        int mid = (lo + hi) >> 1;
        if (batch[mid] < b) lo = mid + 1; else hi = mid;
    }
    off[b] = lo;
}

// ---------------------------------------------------------------------------
// One block per segment: max -> denom -> chunked alpha in LDS -> pooled.
constexpr int CHUNK = 512;
__global__ __launch_bounds__(256) void pool_kernel(
    const float* __restrict__ x, const float* __restrict__ s,
    const int* __restrict__ off, float* __restrict__ pooled) {
    const int b = blockIdx.x;
    const int t = threadIdx.x;
    const int beg = off[b], end = off[b + 1];
    __shared__ float red[256];
    __shared__ float alpha[CHUNK];

    float m = -INFINITY;
    for (int i = beg + t; i < end; i += 256) m = fmaxf(m, s[i]);
    red[t] = m;
    __syncthreads();
    for (int k = 128; k > 0; k >>= 1) {
        if (t < k) red[t] = fmaxf(red[t], red[t + k]);
        __syncthreads();
    }
    m = red[0];
    __syncthreads();

    float dsum = 0.f;
    for (int i = beg + t; i < end; i += 256) dsum += __expf(s[i] - m);
    red[t] = dsum;
    __syncthreads();
    for (int k = 128; k > 0; k >>= 1) {
        if (t < k) red[t] += red[t + k];
        __syncthreads();
    }
    float dinv = red[0] > 0.f ? 1.f / red[0] : 0.f;

    float acc = 0.f;
    for (int c = beg; c < end; c += CHUNK) {
        int len = min(CHUNK, end - c);
        __syncthreads();
        for (int i = t; i < len; i += 256)
            alpha[i] = __expf(s[c + i] - m) * dinv;
        __syncthreads();
        for (int i = 0; i < len; ++i)
            acc += alpha[i] * x[(size_t)(c + i) * D + t];  // coalesced rows
    }
    pooled[(size_t)b * D + t] = acc;
}

// ---------------------------------------------------------------------------
// out = pooled @ Wp + bp. 8 rows/block; P staged transposed [k][r] so the
// k-loop reads two broadcast b128s; Wp streamed coalesced (L2-resident).
__global__ __launch_bounds__(256) void out_gemm_kernel(
    const float* __restrict__ pooled, const float* __restrict__ Wp,
    const float* __restrict__ bp, float* __restrict__ out) {
    constexpr int GR = 8;
    int rb = blockIdx.x * GR;
    int j = threadIdx.x;
    __shared__ float P[D * GR];  // [k][r]
    for (int i = threadIdx.x; i < GR * D; i += 256) {
        int r = i >> 8, k = i & 255;
        P[k * GR + r] = pooled[(size_t)(rb + r) * D + k];
    }
    __syncthreads();
    float acc[GR];
#pragma unroll
    for (int r = 0; r < GR; ++r) acc[r] = 0.f;
    for (int k = 0; k < D; ++k) {
        float w = Wp[(size_t)k * D + j];
        const float4* p4 = (const float4*)(&P[k * GR]);
        float4 a = p4[0], c = p4[1];
        acc[0] += a.x * w; acc[1] += a.y * w; acc[2] += a.z * w; acc[3] += a.w * w;
        acc[4] += c.x * w; acc[5] += c.y * w; acc[6] += c.z * w; acc[7] += c.w * w;
    }
    float bj = bp[j];
#pragma unroll
    for (int r = 0; r < GR; ++r) out[(size_t)(rb + r) * D + j] = acc[r] + bj;
}

// ---------------------------------------------------------------------------
extern "C" void kernel_launch(void* const* d_in, const int* in_sizes, int n_in,
                              void* d_out, int out_size, void* d_ws, size_t ws_size,
                              hipStream_t stream) {
    const float* x     = (const float*)d_in[0];
    const int*   batch = (const int*)d_in[1];
    const float* W1    = (const float*)d_in[2];
    const float* b1    = (const float*)d_in[3];
    const float* w2    = (const float*)d_in[4];
    // d_in[5] = b2: constant shift, cancels in softmax — unused.
    const float* Wp    = (const float*)d_in[6];
    const float* bp    = (const float*)d_in[7];
    float* out = (float*)d_out;
    const int N = in_sizes[1];      // 1,000,000
    const int B = out_size / D;     // 4096

    // ws layout: wfrag(128KB) | s(4*N) | off(4*(B+1)) | pooled(4*B*D)
    char* w = (char*)d_ws;
    bf16_t* wfrag = (bf16_t*)w;
    size_t off_s = 131072;
    float* s = (float*)(w + off_s);
    size_t off_off = off_s + (size_t)4 * N;
    int* off = (int*)(w + off_off);
    size_t off_pooled = (off_off + 4 * (size_t)(B + 1) + 15) & ~(size_t)15;
    float* pooled = (float*)(w + off_pooled);

    hipLaunchKernelGGL(prep_wfrag_kernel, dim3(32), dim3(256), 0, stream,
                       W1, wfrag);
    int nb = (N + 255) / 256;
    hipLaunchKernelGGL(scores_kernel, dim3(nb), dim3(256), 0, stream,
                       x, wfrag, b1, w2, s, N);
    hipLaunchKernelGGL(seg_offsets_kernel, dim3((B + 1 + 255) / 256), dim3(256),
                       0, stream, batch, off, N, B);
    hipLaunchKernelGGL(pool_kernel, dim3(B), dim3(256), 0, stream,
                       x, s, off, pooled);
    hipLaunchKernelGGL(out_gemm_kernel, dim3(B / 8), dim3(256), 0, stream,
                       pooled, Wp, bp, out);
}